// Round 13
// baseline (198.893 us; speedup 1.0000x reference)
//
#include <hip/hip_runtime.h>

#define SB   2048   // sequence length S
#define DD   1024   // model dim D
#define NH   16     // heads
#define HDIM 64     // head dim
#define NB   2      // batch

typedef float f4 __attribute__((ext_vector_type(4)));
typedef __bf16 bf16x8 __attribute__((ext_vector_type(8)));
typedef unsigned short u16;
typedef unsigned int u32;
typedef unsigned long long u64;
typedef u16 u16x8 __attribute__((ext_vector_type(8)));
typedef u16 u16x4 __attribute__((ext_vector_type(4)));

// Q is pre-scaled by 1/sqrt(HD) * log2(e) so attention works in exp2 domain.
#define QSCALE 0.1803368801111f

__device__ __forceinline__ u16 f2bf(float f) {
  unsigned u = __float_as_uint(f);
  u += 0x7FFFu + ((u >> 16) & 1u);   // RNE to bf16
  return (u16)(u >> 16);
}

// async global->LDS, 16 B per lane; LDS dest = base + lane*16 (wave-uniform base)
typedef __attribute__((address_space(3))) unsigned int lds_uint;
typedef __attribute__((address_space(1))) const unsigned int glb_uint;
__device__ __forceinline__ void gl_lds16(const void* g, void* l) {
  __builtin_amdgcn_global_load_lds((glb_uint*)g, (lds_uint*)l, 16, 0, 0);
}

__device__ __forceinline__ void cvt8(const float* __restrict__ src,
                                     u16* __restrict__ dst, size_t i) {
  f4 a = *(const f4*)(src + 8 * i);
  f4 b = *(const f4*)(src + 8 * i + 4);
  u16x8 o;
  o[0] = f2bf(a[0]); o[1] = f2bf(a[1]); o[2] = f2bf(a[2]); o[3] = f2bf(a[3]);
  o[4] = f2bf(b[0]); o[5] = f2bf(b[1]); o[6] = f2bf(b[2]); o[7] = f2bf(b[3]);
  *(u16x8*)(dst + 8 * i) = o;
}

// Non-temporal variant for BROADCAST data (weights read by all 8 XCDs):
// avoids leaving dirty lines in the producer's L2, which would force a
// flush+refetch round-trip on every cross-XCD read (R12 counters).
__device__ __forceinline__ void cvt8_nt(const float* __restrict__ src,
                                        u16* __restrict__ dst, size_t i) {
  f4 a = *(const f4*)(src + 8 * i);
  f4 b = *(const f4*)(src + 8 * i + 4);
  u16x8 o;
  o[0] = f2bf(a[0]); o[1] = f2bf(a[1]); o[2] = f2bf(a[2]); o[3] = f2bf(a[3]);
  o[4] = f2bf(b[0]); o[5] = f2bf(b[1]); o[6] = f2bf(b[2]); o[7] = f2bf(b[3]);
  __builtin_nontemporal_store(o, (u16x8*)(dst + 8 * i));
}

// ---------------- prep: x cvt + Wq/Wk/Wv (+Wo) cvt + RoPE tables ----------
// x blocks XCD-PERMUTED (R12-proven: FETCH/WRITE both dropped): block on
// XCD g converts xb rows [512g, 512g+512) = gemm_qkv XCD g's m-panel ->
// xb lands dirty in the CONSUMER's L2. Weights use NON-TEMPORAL stores
// (broadcast data: all XCDs read every panel; placement can't help).
__global__ __launch_bounds__(256) void prep_kernel(
    const float* __restrict__ x, const float* __restrict__ Wq,
    const float* __restrict__ Wk, const float* __restrict__ Wv,
    const float* __restrict__ Wo,
    u16* __restrict__ xb, u16* __restrict__ Wb3, u16* __restrict__ WoB,
    float* __restrict__ cosT, float* __restrict__ sinT, int nwo) {
  int bid = blockIdx.x, t = threadIdx.x;
  if (bid < 2048) {
    int b2 = ((bid & 7) << 8) | (bid >> 3);   // bijective XCD-match permutation
    cvt8(x, xb, (size_t)b2 * 256 + t);
  } else if (bid < 2560) {
    cvt8_nt(Wq, Wb3, (size_t)(bid - 2048) * 256 + t);
  } else if (bid < 3072) {
    cvt8_nt(Wk, Wb3 + (1u << 20), (size_t)(bid - 2560) * 256 + t);
  } else if (bid < 3584) {
    cvt8_nt(Wv, Wb3 + (2u << 20), (size_t)(bid - 3072) * 256 + t);
  } else if (bid < 3584 + nwo) {
    cvt8_nt(Wo, WoB, (size_t)(bid - 3584) * 256 + t);
  } else {
    int idx = (bid - 3584 - nwo) * 256 + t;   // 0..65535 = S*32
    int tt = idx & 31, s = idx >> 5;
    float inv = powf(10000.0f, -2.0f * (float)tt / 64.0f);
    float ang = (float)s * inv;
    cosT[idx] = cosf(ang);
    sinT[idx] = sinf(ang);
  }
}

// ---------------- fp32 -> bf16 bulk convert (Wo fallback path) ------------
__global__ __launch_bounds__(256) void cvt_bf16_kernel(const float* __restrict__ src,
                                                       u16* __restrict__ dst) {
  cvt8_nt(src, dst, (size_t)blockIdx.x * 256 + threadIdx.x);
}

// ---------------- Fused QKV GEMM: 128x128 tile, BK=64, 512 threads --------
// (R11/R12-proven.) 1-D grid 768, XCD-decoded: m0 panel owned by XCD lid&7.
// 8 waves of 32x64 output tiles; acc 2x4; 16 MFMA/iter; 32 KB LDS;
// granule swizzle phys = lg ^ (row & 7); stage->sync->compute->sync.
// Epilogue (V): k-permuted merged u16x8. Epilogue (Q/K): 2-pass per-wave
// LDS transpose + streaming RoPE.
__global__ __launch_bounds__(512, 4) void gemm_qkv_fused_kernel(
    const u16* __restrict__ A, const u16* __restrict__ W3,
    const float* __restrict__ bq, const float* __restrict__ bk,
    const float* __restrict__ bv,
    u16* __restrict__ Qw, u16* __restrict__ Kw, u16* __restrict__ Vt,
    const float* __restrict__ cosT, const float* __restrict__ sinT) {
  const int K = DD;
  __shared__ char smem[32768];
  u16* As = (u16*)smem;              // 16 KB: 128 rows x 64
  u16* Bs = (u16*)(smem + 16384);    // 16 KB
  const int t = threadIdx.x;
  const int wave = t >> 6, lane = t & 63;
  const int lid = blockIdx.x;                      // 0..767
  const int m0 = ((lid & 7) * 4 + ((lid >> 3) & 3)) * 128;
  const int n0 = (lid >> 5) * 128;
  const int mw = (wave >> 1) * 32, nw = (wave & 1) * 64;
  const int quad = lane >> 4, l15 = lane & 15;
  const int srow = lane >> 3, sgran = lane & 7;   // staging: 8 rows x 8 granules
  const u16* Ab = A + (size_t)m0 * K;
  const u16* Bb = W3 + (size_t)n0 * K;
  f4 acc[2][4];
#pragma unroll
  for (int i = 0; i < 2; i++)
#pragma unroll
    for (int j = 0; j < 4; j++) acc[i][j] = (f4)0.f;

  for (int kt = 0; kt < K; kt += 64) {
#pragma unroll
    for (int is = 0; is < 2; is++) {
      int r = wave * 16 + is * 8 + srow;
      int lg = sgran ^ (r & 7);
      gl_lds16(Ab + (size_t)r * K + kt + lg * 8, &As[(wave * 16 + is * 8) * 64]);
      gl_lds16(Bb + (size_t)r * K + kt + lg * 8, &Bs[(wave * 16 + is * 8) * 64]);
    }
    __syncthreads();
#pragma unroll
    for (int kh = 0; kh < 2; kh++) {
      bf16x8 af[2], bfr[4];
#pragma unroll
      for (int i = 0; i < 2; i++) {
        int R = mw + 16 * i + l15;
        af[i] = *(const bf16x8*)&As[R * 64 + ((kh * 4 + quad) ^ (R & 7)) * 8];
      }
#pragma unroll
      for (int j = 0; j < 4; j++) {
        int Rb = nw + 16 * j + l15;
        bfr[j] = *(const bf16x8*)&Bs[Rb * 64 + ((kh * 4 + quad) ^ (Rb & 7)) * 8];
      }
#pragma unroll
      for (int i = 0; i < 2; i++)
#pragma unroll
        for (int j = 0; j < 4; j++)
          acc[i][j] = __builtin_amdgcn_mfma_f32_16x16x32_bf16(af[i], bfr[j],
                                                              acc[i][j], 0, 0, 0);
    }
    __syncthreads();
  }

  // ---- epilogue: block n-range (128) never crosses a 1024 boundary -> the
  // output routing (Q/K/V) is block-uniform.
  const int which = n0 >> 10;                    // 0=Q 1=K 2=V
  const int hh = ((n0 & 1023) + nw) >> 6;        // head index (wave-uniform)
  const int cb = (n0 + nw) & 1023;               // col base, multiple of 64

  if (which == 2) {
    // V: transposed store (B,H,HD,S), k-permuted within 32-blocks.
#pragma unroll
    for (int j = 0; j < 4; j++) {
      const int dh = 16 * j + l15;
      const float bval = bv[cb + 16 * j + l15];
      int mg0 = m0 + mw;
      int b = mg0 >> 11, sr0 = mg0 & (SB - 1);
      u16x8 o;
#pragma unroll
      for (int r = 0; r < 4; r++) o[r] = f2bf(acc[0][j][r] + bval);
#pragma unroll
      for (int r = 0; r < 4; r++) o[4 + r] = f2bf(acc[1][j][r] + bval);
      *(u16x8*)(Vt + ((size_t)(b * NH + hh) * HDIM + dh) * SB +
                (sr0 | (quad << 3))) = o;
    }
  } else {
    // Q/K: LDS transpose -> in-register RoPE -> coalesced u16x8 stores.
    // 2 passes over the 4 x 8 KB slices (waves 0-3, then 4-7).
    u16* dst = which ? Kw : Qw;
    const float* barr = which ? bk : bq;
    const float scale = which ? 1.0f : QSCALE;
    float bvj[4];
#pragma unroll
    for (int j = 0; j < 4; j++) bvj[j] = barr[cb + 16 * j + l15];
    const int kk = lane >> 1, hf = lane & 1;
#pragma unroll
    for (int pass = 0; pass < 2; pass++) {
      if ((wave >> 2) == pass) {
        float* sl = (float*)(smem + (wave & 3) * 8192);  // 32 rows x 64 f32
        // write phase: lane(quad,l15) scatters acc into [row][rot(col)]
#pragma unroll
        for (int il = 0; il < 2; il++) {
#pragma unroll
          for (int j = 0; j < 4; j++) {
            const int q = 4 * j + (l15 >> 2);
            const int w = l15 & 3;
#pragma unroll
            for (int r = 0; r < 4; r++) {
              const int row = il * 16 + quad * 4 + r;
              sl[(row << 6) + (((q + row) & 15) << 2) + w] =
                  (acc[il][j][r] + bvj[j]) * scale;
            }
          }
        }
        asm volatile("s_waitcnt lgkmcnt(0)" ::: "memory");
        // read phase (STREAMING): lane -> (row kk, col-half hf*32).
        const int m = m0 + mw + kk;
        const int b = m >> 11, sr = m & (SB - 1);
        const float* ct = cosT + sr * 32 + hf * 16;
        const float* st2 = sinT + sr * 32 + hf * 16;
        u16* op = dst + (((size_t)(b * NH + hh)) * SB + sr) * HDIM + hf * 32;
#pragma unroll
        for (int q8 = 0; q8 < 4; q8++) {
          f4 c4 = *(const f4*)(ct + q8 * 4);
          f4 s4 = *(const f4*)(st2 + q8 * 4);
          const int qc0 = hf * 8 + q8 * 2;       // two consecutive col-quads
          f4 v0 = *(const f4*)(sl + (kk << 6) + (((qc0 + kk) & 15) << 2));
          f4 v1 = *(const f4*)(sl + (kk << 6) + (((qc0 + 1 + kk) & 15) << 2));
          u16x8 o;
          o[0] = f2bf(v0[0] * c4[0] - v0[1] * s4[0]);
          o[1] = f2bf(v0[0] * s4[0] + v0[1] * c4[0]);
          o[2] = f2bf(v0[2] * c4[1] - v0[3] * s4[1]);
          o[3] = f2bf(v0[2] * s4[1] + v0[3] * c4[1]);
          o[4] = f2bf(v1[0] * c4[2] - v1[1] * s4[2]);
          o[5] = f2bf(v1[0] * s4[2] + v1[1] * c4[2]);
          o[6] = f2bf(v1[2] * c4[3] - v1[3] * s4[3]);
          o[7] = f2bf(v1[2] * s4[3] + v1[3] * c4[3]);
          *(u16x8*)(op + q8 * 8) = o;
        }
      }
      __syncthreads();   // pass-0 LDS reads drained before pass-1 reuses slices
    }
  }
}

// ---------------- Output projection GEMM: 128x64 tile, BK=64, 256 thr -----
// R10/R11-PROVEN version (R12's 512-thread 32x32/wave variant regressed
// ~+6 us: only 8 MFMA between barriers — barrier-bound, same as R7 lesson).
// 1-D grid 512, XCD-decoded: g = lid&7, mb = g*4 + (lid>>3&3), nb = lid>>5.
__global__ __launch_bounds__(256) void gemm_out_kernel(
    const u16* __restrict__ A, const u16* __restrict__ W,
    const float* __restrict__ bias, float* __restrict__ outp) {
  const int K = DD;
  __shared__ u16 As[128 * 64];   // 16 KB
  __shared__ u16 Bs[64 * 64];    // 8 KB
  const int t = threadIdx.x;
  const int wave = t >> 6, lane = t & 63;
  const int lid = blockIdx.x;                      // 0..511
  const int m0 = ((lid & 7) * 4 + ((lid >> 3) & 3)) * 128;
  const int n0 = (lid >> 5) * 64;
  const int mw = (wave >> 1) * 64, nw = (wave & 1) * 32;
  const int quad = lane >> 4, l15 = lane & 15;
  const int srow = lane >> 3, sgran = lane & 7;
  const u16* Ab = A + (size_t)m0 * K;
  const u16* Bb = W + (size_t)n0 * K;
  f4 acc[4][2];
#pragma unroll
  for (int i = 0; i < 4; i++)
#pragma unroll
    for (int j = 0; j < 2; j++) acc[i][j] = (f4)0.f;

  for (int kt = 0; kt < K; kt += 64) {
#pragma unroll
    for (int is = 0; is < 4; is++) {
      int r = wave * 32 + is * 8 + srow;
      int lg = sgran ^ (r & 7);
      gl_lds16(Ab + (size_t)r * K + kt + lg * 8, &As[(wave * 32 + is * 8) * 64]);
    }
#pragma unroll
    for (int is = 0; is < 2; is++) {
      int r = wave * 16 + is * 8 + srow;
      int lg = sgran ^ (r & 7);
      gl_lds16(Bb + (size_t)r * K + kt + lg * 8, &Bs[(wave * 16 + is * 8) * 64]);
    }
    __syncthreads();
#pragma unroll
    for (int kh = 0; kh < 2; kh++) {
      bf16x8 af[4], bfr[2];
#pragma unroll
      for (int i = 0; i < 4; i++) {
        int R = mw + 16 * i + l15;
        af[i] = *(const bf16x8*)&As[R * 64 + ((kh * 4 + quad) ^ (R & 7)) * 8];
      }
#pragma unroll
      for (int j = 0; j < 2; j++) {
        int R = nw + 16 * j + l15;
        bfr[j] = *(const bf16x8*)&Bs[R * 64 + ((kh * 4 + quad) ^ (R & 7)) * 8];
      }
#pragma unroll
      for (int i = 0; i < 4; i++)
#pragma unroll
        for (int j = 0; j < 2; j++)
          acc[i][j] = __builtin_amdgcn_mfma_f32_16x16x32_bf16(af[i], bfr[j],
                                                              acc[i][j], 0, 0, 0);
    }
    __syncthreads();
  }
#pragma unroll
  for (int i = 0; i < 4; i++)
#pragma unroll
    for (int j = 0; j < 2; j++) {
      int colg = n0 + nw + 16 * j + l15;
#pragma unroll
      for (int r = 0; r < 4; r++) {
        int mg = m0 + mw + 16 * i + quad * 4 + r;
        outp[(size_t)mg * DD + colg] = acc[i][j][r] + bias[colg];
      }
    }
}

// ---------------- MFMA flash attention: split-pair blocks, 8 waves --------
// (R9-proven.) Grid 512: each (qp,h,b) pair splits into two `half` blocks;
// waves 0-3 light tile (QT=qp), waves 4-7 heavy mirror (QT=15-qp); each
// wave owns ONE 16-row strip. 2 blocks/CU x 8 waves = 4 waves/SIMD.
// XCD swizzle: all 16 blocks of a (b,h) share lid mod 32 -> same XCD.
// PV B-operand = LANE-LOCAL P (V stored k-permuted by gemm_qkv).
__global__ __launch_bounds__(512) void attn_mfma_kernel(
    const u16* __restrict__ Qw, const u16* __restrict__ Kw,
    const u16* __restrict__ Vt, u16* __restrict__ Ow,
    const int* __restrict__ eff) {
  __shared__ u16 KL[2][8 * 64 * 8];   // [buf][frag fk=mt*2+j][lane][8] : 8 KB/buf
  __shared__ u16 VL[2][8 * 64 * 8];   // [buf][frag fv=dt*2+j][lane][8]
  const int w = threadIdx.x >> 6, lane = threadIdx.x & 63;
  const int l15 = lane & 15, q4 = lane >> 4;
  const int lid = blockIdx.x;
  const int qp = lid >> 6;                               // 0..7
  const int half = (lid >> 5) & 1;                       // 64-row half of tile
  const int c  = lid & 31;
  const int h = c & 15, b = c >> 4;
  const int wg = w >> 2, wl = w & 3;
  const int QT = wg ? (SB / 128 - 1 - qp) : qp;          // light / heavy pair
  const int limit = SB - eff[b];                         // valid cols [0, limit)
  const size_t bh = ((size_t)b * NH + h) * (SB * HDIM);

  const int rowbase = QT * 128 + half * 64 + wl * 16;    // 16-row strip per wave

  bf16x8 qf[2];
  {
    const u16* qp0 = Qw + bh + (size_t)(rowbase + l15) * HDIM + q4 * 8;
    qf[0] = *(const bf16x8*)qp0;
    qf[1] = *(const bf16x8*)(qp0 + 32);
  }

  f4 acc[4];
#pragma unroll
  for (int dt = 0; dt < 4; dt++) acc[dt] = (f4)0.f;
  float l_run = 0.f;   // per-lane partial row sum (16 cols/lane)

  // block-uniform tile count = heavy tile's k-range (same for both halves)
  const int kendB = min((SB / 128 - 1 - qp) * 128 + 127, limit - 1);
  const int ntiles = (kendB >> 6) + 1;
  const int wkend = min(rowbase + 15, limit - 1);

  // stage(tile, buf): wave w stages frags {2w, 2w+1} of 16 (0-7 K, 8-15 V).
#define STAGE_TILE(TILE, BUF)                                                   \
  {                                                                             \
    const int colb_ = (TILE) * 64;                                              \
    _Pragma("unroll") for (int f = 0; f < 2; f++) {                             \
      int fr = w * 2 + f;                                                       \
      if (fr < 8) {                                                             \
        int mt = fr >> 1, j = fr & 1;                                           \
        gl_lds16(Kw + bh + (size_t)(colb_ + mt * 16 + l15) * HDIM + q4 * 8 + j * 32, \
                 &KL[BUF][fr * 512]);                                           \
      } else {                                                                  \
        int fv = fr - 8, dt = fv >> 1, j = fv & 1;                              \
        gl_lds16(Vt + bh + (size_t)(dt * 16 + l15) * SB + colb_ + q4 * 8 + j * 32, \
                 &VL[BUF][fv * 512]);                                           \
      }                                                                         \
    }                                                                           \
  }

  STAGE_TILE(0, 0)
  __syncthreads();

  for (int kt = 0; kt < ntiles; kt++) {
    const int cur = kt & 1;
    const int colb = kt * 64;
    if (kt + 1 < ntiles) STAGE_TILE(kt + 1, cur ^ 1)

    if (colb <= wkend) {   // wave-uniform: tile has at least one valid col
      // ---- S^T = K · Q^T (K frags from LDS) ----
      f4 sa[4];
      __builtin_amdgcn_s_setprio(1);
#pragma unroll
      for (int mt = 0; mt < 4; mt++) {
        bf16x8 k0 = *(const bf16x8*)&KL[cur][(mt * 2 + 0) * 512 + lane * 8];
        bf16x8 k1 = *(const bf16x8*)&KL[cur][(mt * 2 + 1) * 512 + lane * 8];
        f4 s0 = (f4)0.f;
        s0 = __builtin_amdgcn_mfma_f32_16x16x32_bf16(k0, qf[0], s0, 0, 0, 0);
        s0 = __builtin_amdgcn_mfma_f32_16x16x32_bf16(k1, qf[1], s0, 0, 0, 0);
        sa[mt] = s0;
      }
      __builtin_amdgcn_s_setprio(0);

      // ---- mask + fixed-reference softmax weights ----
      u32 pk[4][2];
      {
        const int rg = rowbase + l15;
        const bool needmask = (colb + 63 > rowbase) || (colb + 63 >= limit);
        if (needmask) {
#pragma unroll
          for (int mt = 0; mt < 4; mt++)
#pragma unroll
            for (int r = 0; r < 4; r++) {
              int col = colb + mt * 16 + q4 * 4 + r;
              if (col > rg || col >= limit) sa[mt][r] = -3.0e38f;
            }
        }
        float lsum = 0.f;
#pragma unroll
        for (int mt = 0; mt < 4; mt++) {
          float p0 = exp2f(sa[mt][0]);   // masked -> exp2(-3e38) = 0 exactly
          float p1 = exp2f(sa[mt][1]);
          float p2 = exp2f(sa[mt][2]);
          float p3 = exp2f(sa[mt][3]);
          lsum += (p0 + p1) + (p2 + p3);
          pk[mt][0] = (__float_as_uint(p1) & 0xFFFF0000u) | (__float_as_uint(p0) >> 16);
          pk[mt][1] = (__float_as_uint(p3) & 0xFFFF0000u) | (__float_as_uint(p2) >> 16);
        }
        l_run += lsum;
      }

      // ---- PV: B-operand = LANE-LOCAL packed P (k-perm matches Vt) ----
      union { u32 wds[4]; bf16x8 v; } ub0, ub1;
      ub0.wds[0] = pk[0][0]; ub0.wds[1] = pk[0][1];
      ub0.wds[2] = pk[1][0]; ub0.wds[3] = pk[1][1];
      ub1.wds[0] = pk[2][0]; ub1.wds[1] = pk[2][1];
      ub1.wds[2] = pk[3][0]; ub1.wds[3] = pk[3][1];
      __builtin_amdgcn_s_setprio(1);
#pragma unroll
      for (int dt = 0; dt < 4; dt++) {
        bf16x8 v0 = *(const bf16x8*)&VL[cur][(dt * 2 + 0) * 512 + lane * 8];
        bf16x8 v1 = *(const bf16x8*)&VL[cur][(dt * 2 + 1) * 512 + lane * 8];
        acc[dt] = __builtin_amdgcn_mfma_f32_16x16x32_bf16(v0, ub0.v, acc[dt], 0, 0, 0);
        acc[dt] = __builtin_amdgcn_mfma_f32_16x16x32_bf16(v1, ub1.v, acc[dt], 0, 0, 0);
      }
      __builtin_amdgcn_s_setprio(0);
    }
    __syncthreads();   // reads of buf cur done; prefetch into cur^1 drained
  }

  // ---- epilogue: reduce l across lanes, normalize, store (B,S,H,HD) ----
  {
    float lt = l_run;
    lt += __shfl_xor(lt, 16);
    lt += __shfl_xor(lt, 32);
    const float linv = 1.0f / lt;
    const int rg = rowbase + l15;
    const size_t obase = (((size_t)b * SB + rg) * NH + h) * HDIM + q4 * 4;
#pragma unroll
    for (int dt = 0; dt < 4; dt++) {
      u16x4 o;
      o[0] = f2bf(acc[dt][0] * linv);
      o[1] = f2bf(acc[dt][1] * linv);
      o[2] = f2bf(acc[dt][2] * linv);
      o[3] = f2bf(acc[dt][3] * linv);
      *(u16x4*)(Ow + obase + dt * 16) = o;
    }
  }
}

extern "C" void kernel_launch(void* const* d_in, const int* in_sizes, int n_in,
                              void* d_out, int out_size, void* d_ws, size_t ws_size,
                              hipStream_t stream) {
  (void)in_sizes; (void)n_in; (void)out_size;
  const float* x  = (const float*)d_in[0];
  const int*   eff = (const int*)d_in[1];
  const float* Wq = (const float*)d_in[2];
  const float* bq = (const float*)d_in[3];
  const float* Wk = (const float*)d_in[4];
  const float* bk = (const float*)d_in[5];
  const float* Wv = (const float*)d_in[6];
  const float* bv = (const float*)d_in[7];
  const float* Wo = (const float*)d_in[8];
  const float* bo = (const float*)d_in[9];
  float* out = (float*)d_out;

  char* ws = (char*)d_ws;
  u16* Qw = (u16*)(ws);                        // 8 MB  bf16 (B,H,S,HD), pre-scaled
  u16* Kw = (u16*)(ws + (8u << 20));           // 8 MB  bf16 (B,H,S,HD)
  u16* Vt = (u16*)(ws + (16u << 20));          // 8 MB  bf16 (B,H,HD,S)  transposed+k-perm
  u16* Ow = (u16*)(ws + (24u << 20));          // 8 MB  bf16 (B,S,H,HD)
  u16* xb = (u16*)(ws + (24u << 20));          // aliases Ow: xb dead before attn writes Ow
  u16* Wb3 = (u16*)(ws + (32u << 20));         // 6 MB  stacked bf16 [Wq;Wk;Wv]
  float* cosT = (float*)(ws + (38u << 20));    // 256 KB
  float* sinT = (float*)(ws + (38u << 20) + (256u << 10));

  // Wo bf16: separate region if workspace allows (fused cvt in prep, one
  // fewer dispatch); else fall back to reusing Wb3 after gemm_qkv.
  size_t wob_off = (38u << 20) + (512u << 10);
  int nwo = (ws_size >= wob_off + (2u << 20)) ? 512 : 0;
  u16* WoB = nwo ? (u16*)(ws + wob_off) : Wb3;

  hipLaunchKernelGGL(prep_kernel, dim3(3840 + nwo), dim3(256), 0, stream,
                     x, Wq, Wk, Wv, Wo, xb, Wb3, WoB, cosT, sinT, nwo);

  hipLaunchKernelGGL(gemm_qkv_fused_kernel, dim3(768), dim3(512), 0, stream,
                     xb, Wb3, bq, bk, bv, Qw, Kw, Vt, cosT, sinT);

  if (!nwo)
    hipLaunchKernelGGL(cvt_bf16_kernel, dim3(512), dim3(256), 0, stream, Wo, WoB);

  hipLaunchKernelGGL(attn_mfma_kernel, dim3(512), dim3(512), 0, stream,
                     Qw, Kw, Vt, Ow, eff);

  hipLaunchKernelGGL(gemm_out_kernel, dim3(512), dim3(256), 0, stream, Ow, WoB, bo, out);
}

// Round 14
// 184.264 us; speedup vs baseline: 1.0794x; 1.0794x over previous
//
#include <hip/hip_runtime.h>

#define SB   2048   // sequence length S
#define DD   1024   // model dim D
#define NH   16     // heads
#define HDIM 64     // head dim
#define NB   2      // batch

typedef float f4 __attribute__((ext_vector_type(4)));
typedef __bf16 bf16x8 __attribute__((ext_vector_type(8)));
typedef unsigned short u16;
typedef unsigned int u32;
typedef unsigned long long u64;
typedef u16 u16x8 __attribute__((ext_vector_type(8)));
typedef u16 u16x4 __attribute__((ext_vector_type(4)));

// Q is pre-scaled by 1/sqrt(HD) * log2(e) so attention works in exp2 domain.
#define QSCALE 0.1803368801111f

__device__ __forceinline__ u16 f2bf(float f) {
  unsigned u = __float_as_uint(f);
  u += 0x7FFFu + ((u >> 16) & 1u);   // RNE to bf16
  return (u16)(u >> 16);
}

// async global->LDS, 16 B per lane; LDS dest = base + lane*16 (wave-uniform base)
typedef __attribute__((address_space(3))) unsigned int lds_uint;
typedef __attribute__((address_space(1))) const unsigned int glb_uint;
__device__ __forceinline__ void gl_lds16(const void* g, void* l) {
  __builtin_amdgcn_global_load_lds((glb_uint*)g, (lds_uint*)l, 16, 0, 0);
}

__device__ __forceinline__ void cvt8(const float* __restrict__ src,
                                     u16* __restrict__ dst, size_t i) {
  f4 a = *(const f4*)(src + 8 * i);
  f4 b = *(const f4*)(src + 8 * i + 4);
  u16x8 o;
  o[0] = f2bf(a[0]); o[1] = f2bf(a[1]); o[2] = f2bf(a[2]); o[3] = f2bf(a[3]);
  o[4] = f2bf(b[0]); o[5] = f2bf(b[1]); o[6] = f2bf(b[2]); o[7] = f2bf(b[3]);
  *(u16x8*)(dst + 8 * i) = o;
}

// ---------------- prep: x cvt + Wq/Wk/Wv (+Wo) cvt + RoPE tables ----------
// x blocks XCD-PERMUTED (R12-proven: qkv 51->44.5 us): block on XCD g
// converts xb rows [512g, 512g+512) = gemm_qkv XCD g's m-panel -> xb lands
// dirty in the CONSUMER's L2. Weights use NORMAL stores (R13 falsified NT:
// same FETCH bytes but +12 us — NT pushes data past L3, consumers pay HBM
// latency instead of L3 latency).
__global__ __launch_bounds__(256) void prep_kernel(
    const float* __restrict__ x, const float* __restrict__ Wq,
    const float* __restrict__ Wk, const float* __restrict__ Wv,
    const float* __restrict__ Wo,
    u16* __restrict__ xb, u16* __restrict__ Wb3, u16* __restrict__ WoB,
    float* __restrict__ cosT, float* __restrict__ sinT, int nwo) {
  int bid = blockIdx.x, t = threadIdx.x;
  if (bid < 2048) {
    int b2 = ((bid & 7) << 8) | (bid >> 3);   // bijective XCD-match permutation
    cvt8(x, xb, (size_t)b2 * 256 + t);
  } else if (bid < 2560) {
    cvt8(Wq, Wb3, (size_t)(bid - 2048) * 256 + t);
  } else if (bid < 3072) {
    cvt8(Wk, Wb3 + (1u << 20), (size_t)(bid - 2560) * 256 + t);
  } else if (bid < 3584) {
    cvt8(Wv, Wb3 + (2u << 20), (size_t)(bid - 3072) * 256 + t);
  } else if (bid < 3584 + nwo) {
    cvt8(Wo, WoB, (size_t)(bid - 3584) * 256 + t);
  } else {
    int idx = (bid - 3584 - nwo) * 256 + t;   // 0..65535 = S*32
    int tt = idx & 31, s = idx >> 5;
    float inv = powf(10000.0f, -2.0f * (float)tt / 64.0f);
    float ang = (float)s * inv;
    cosT[idx] = cosf(ang);
    sinT[idx] = sinf(ang);
  }
}

// ---------------- fp32 -> bf16 bulk convert (Wo fallback path) ------------
__global__ __launch_bounds__(256) void cvt_bf16_kernel(const float* __restrict__ src,
                                                       u16* __restrict__ dst) {
  cvt8(src, dst, (size_t)blockIdx.x * 256 + threadIdx.x);
}

// ---------------- Fused QKV GEMM: 128x128 tile, BK=64, 512 threads --------
// (R11/R12-proven.) 1-D grid 768, XCD-decoded: m0 panel owned by XCD lid&7.
// 8 waves of 32x64 output tiles; acc 2x4; 16 MFMA/iter; 32 KB LDS;
// granule swizzle phys = lg ^ (row & 7); stage->sync->compute->sync.
// Epilogue (V): k-permuted merged u16x8. Epilogue (Q/K): 2-pass per-wave
// LDS transpose + streaming RoPE.
__global__ __launch_bounds__(512, 4) void gemm_qkv_fused_kernel(
    const u16* __restrict__ A, const u16* __restrict__ W3,
    const float* __restrict__ bq, const float* __restrict__ bk,
    const float* __restrict__ bv,
    u16* __restrict__ Qw, u16* __restrict__ Kw, u16* __restrict__ Vt,
    const float* __restrict__ cosT, const float* __restrict__ sinT) {
  const int K = DD;
  __shared__ char smem[32768];
  u16* As = (u16*)smem;              // 16 KB: 128 rows x 64
  u16* Bs = (u16*)(smem + 16384);    // 16 KB
  const int t = threadIdx.x;
  const int wave = t >> 6, lane = t & 63;
  const int lid = blockIdx.x;                      // 0..767
  const int m0 = ((lid & 7) * 4 + ((lid >> 3) & 3)) * 128;
  const int n0 = (lid >> 5) * 128;
  const int mw = (wave >> 1) * 32, nw = (wave & 1) * 64;
  const int quad = lane >> 4, l15 = lane & 15;
  const int srow = lane >> 3, sgran = lane & 7;   // staging: 8 rows x 8 granules
  const u16* Ab = A + (size_t)m0 * K;
  const u16* Bb = W3 + (size_t)n0 * K;
  f4 acc[2][4];
#pragma unroll
  for (int i = 0; i < 2; i++)
#pragma unroll
    for (int j = 0; j < 4; j++) acc[i][j] = (f4)0.f;

  for (int kt = 0; kt < K; kt += 64) {
#pragma unroll
    for (int is = 0; is < 2; is++) {
      int r = wave * 16 + is * 8 + srow;
      int lg = sgran ^ (r & 7);
      gl_lds16(Ab + (size_t)r * K + kt + lg * 8, &As[(wave * 16 + is * 8) * 64]);
      gl_lds16(Bb + (size_t)r * K + kt + lg * 8, &Bs[(wave * 16 + is * 8) * 64]);
    }
    __syncthreads();
#pragma unroll
    for (int kh = 0; kh < 2; kh++) {
      bf16x8 af[2], bfr[4];
#pragma unroll
      for (int i = 0; i < 2; i++) {
        int R = mw + 16 * i + l15;
        af[i] = *(const bf16x8*)&As[R * 64 + ((kh * 4 + quad) ^ (R & 7)) * 8];
      }
#pragma unroll
      for (int j = 0; j < 4; j++) {
        int Rb = nw + 16 * j + l15;
        bfr[j] = *(const bf16x8*)&Bs[Rb * 64 + ((kh * 4 + quad) ^ (Rb & 7)) * 8];
      }
#pragma unroll
      for (int i = 0; i < 2; i++)
#pragma unroll
        for (int j = 0; j < 4; j++)
          acc[i][j] = __builtin_amdgcn_mfma_f32_16x16x32_bf16(af[i], bfr[j],
                                                              acc[i][j], 0, 0, 0);
    }
    __syncthreads();
  }

  // ---- epilogue: block n-range (128) never crosses a 1024 boundary -> the
  // output routing (Q/K/V) is block-uniform.
  const int which = n0 >> 10;                    // 0=Q 1=K 2=V
  const int hh = ((n0 & 1023) + nw) >> 6;        // head index (wave-uniform)
  const int cb = (n0 + nw) & 1023;               // col base, multiple of 64

  if (which == 2) {
    // V: transposed store (B,H,HD,S), k-permuted within 32-blocks.
#pragma unroll
    for (int j = 0; j < 4; j++) {
      const int dh = 16 * j + l15;
      const float bval = bv[cb + 16 * j + l15];
      int mg0 = m0 + mw;
      int b = mg0 >> 11, sr0 = mg0 & (SB - 1);
      u16x8 o;
#pragma unroll
      for (int r = 0; r < 4; r++) o[r] = f2bf(acc[0][j][r] + bval);
#pragma unroll
      for (int r = 0; r < 4; r++) o[4 + r] = f2bf(acc[1][j][r] + bval);
      *(u16x8*)(Vt + ((size_t)(b * NH + hh) * HDIM + dh) * SB +
                (sr0 | (quad << 3))) = o;
    }
  } else {
    // Q/K: LDS transpose -> in-register RoPE -> coalesced u16x8 stores.
    // 2 passes over the 4 x 8 KB slices (waves 0-3, then 4-7).
    u16* dst = which ? Kw : Qw;
    const float* barr = which ? bk : bq;
    const float scale = which ? 1.0f : QSCALE;
    float bvj[4];
#pragma unroll
    for (int j = 0; j < 4; j++) bvj[j] = barr[cb + 16 * j + l15];
    const int kk = lane >> 1, hf = lane & 1;
#pragma unroll
    for (int pass = 0; pass < 2; pass++) {
      if ((wave >> 2) == pass) {
        float* sl = (float*)(smem + (wave & 3) * 8192);  // 32 rows x 64 f32
        // write phase: lane(quad,l15) scatters acc into [row][rot(col)]
#pragma unroll
        for (int il = 0; il < 2; il++) {
#pragma unroll
          for (int j = 0; j < 4; j++) {
            const int q = 4 * j + (l15 >> 2);
            const int w = l15 & 3;
#pragma unroll
            for (int r = 0; r < 4; r++) {
              const int row = il * 16 + quad * 4 + r;
              sl[(row << 6) + (((q + row) & 15) << 2) + w] =
                  (acc[il][j][r] + bvj[j]) * scale;
            }
          }
        }
        asm volatile("s_waitcnt lgkmcnt(0)" ::: "memory");
        // read phase (STREAMING): lane -> (row kk, col-half hf*32).
        const int m = m0 + mw + kk;
        const int b = m >> 11, sr = m & (SB - 1);
        const float* ct = cosT + sr * 32 + hf * 16;
        const float* st2 = sinT + sr * 32 + hf * 16;
        u16* op = dst + (((size_t)(b * NH + hh)) * SB + sr) * HDIM + hf * 32;
#pragma unroll
        for (int q8 = 0; q8 < 4; q8++) {
          f4 c4 = *(const f4*)(ct + q8 * 4);
          f4 s4 = *(const f4*)(st2 + q8 * 4);
          const int qc0 = hf * 8 + q8 * 2;       // two consecutive col-quads
          f4 v0 = *(const f4*)(sl + (kk << 6) + (((qc0 + kk) & 15) << 2));
          f4 v1 = *(const f4*)(sl + (kk << 6) + (((qc0 + 1 + kk) & 15) << 2));
          u16x8 o;
          o[0] = f2bf(v0[0] * c4[0] - v0[1] * s4[0]);
          o[1] = f2bf(v0[0] * s4[0] + v0[1] * c4[0]);
          o[2] = f2bf(v0[2] * c4[1] - v0[3] * s4[1]);
          o[3] = f2bf(v0[2] * s4[1] + v0[3] * c4[1]);
          o[4] = f2bf(v1[0] * c4[2] - v1[1] * s4[2]);
          o[5] = f2bf(v1[0] * s4[2] + v1[1] * c4[2]);
          o[6] = f2bf(v1[2] * c4[3] - v1[3] * s4[3]);
          o[7] = f2bf(v1[2] * s4[3] + v1[3] * c4[3]);
          *(u16x8*)(op + q8 * 8) = o;
        }
      }
      __syncthreads();   // pass-0 LDS reads drained before pass-1 reuses slices
    }
  }
}

// ---------------- Output projection GEMM: 128x64 tile, BK=64, 256 thr -----
// R10/R11-PROVEN version (512-thread 32x32/wave variant regressed ~+6 us in
// R12: only 8 MFMA between barriers). 1-D grid 512, XCD-decoded:
// g = lid&7, mb = g*4 + (lid>>3&3), nb = lid>>5.
__global__ __launch_bounds__(256) void gemm_out_kernel(
    const u16* __restrict__ A, const u16* __restrict__ W,
    const float* __restrict__ bias, float* __restrict__ outp) {
  const int K = DD;
  __shared__ u16 As[128 * 64];   // 16 KB
  __shared__ u16 Bs[64 * 64];    // 8 KB
  const int t = threadIdx.x;
  const int wave = t >> 6, lane = t & 63;
  const int lid = blockIdx.x;                      // 0..511
  const int m0 = ((lid & 7) * 4 + ((lid >> 3) & 3)) * 128;
  const int n0 = (lid >> 5) * 64;
  const int mw = (wave >> 1) * 64, nw = (wave & 1) * 32;
  const int quad = lane >> 4, l15 = lane & 15;
  const int srow = lane >> 3, sgran = lane & 7;
  const u16* Ab = A + (size_t)m0 * K;
  const u16* Bb = W + (size_t)n0 * K;
  f4 acc[4][2];
#pragma unroll
  for (int i = 0; i < 4; i++)
#pragma unroll
    for (int j = 0; j < 2; j++) acc[i][j] = (f4)0.f;

  for (int kt = 0; kt < K; kt += 64) {
#pragma unroll
    for (int is = 0; is < 4; is++) {
      int r = wave * 32 + is * 8 + srow;
      int lg = sgran ^ (r & 7);
      gl_lds16(Ab + (size_t)r * K + kt + lg * 8, &As[(wave * 32 + is * 8) * 64]);
    }
#pragma unroll
    for (int is = 0; is < 2; is++) {
      int r = wave * 16 + is * 8 + srow;
      int lg = sgran ^ (r & 7);
      gl_lds16(Bb + (size_t)r * K + kt + lg * 8, &Bs[(wave * 16 + is * 8) * 64]);
    }
    __syncthreads();
#pragma unroll
    for (int kh = 0; kh < 2; kh++) {
      bf16x8 af[4], bfr[2];
#pragma unroll
      for (int i = 0; i < 4; i++) {
        int R = mw + 16 * i + l15;
        af[i] = *(const bf16x8*)&As[R * 64 + ((kh * 4 + quad) ^ (R & 7)) * 8];
      }
#pragma unroll
      for (int j = 0; j < 2; j++) {
        int R = nw + 16 * j + l15;
        bfr[j] = *(const bf16x8*)&Bs[R * 64 + ((kh * 4 + quad) ^ (R & 7)) * 8];
      }
#pragma unroll
      for (int i = 0; i < 4; i++)
#pragma unroll
        for (int j = 0; j < 2; j++)
          acc[i][j] = __builtin_amdgcn_mfma_f32_16x16x32_bf16(af[i], bfr[j],
                                                              acc[i][j], 0, 0, 0);
    }
    __syncthreads();
  }
#pragma unroll
  for (int i = 0; i < 4; i++)
#pragma unroll
    for (int j = 0; j < 2; j++) {
      int colg = n0 + nw + 16 * j + l15;
#pragma unroll
      for (int r = 0; r < 4; r++) {
        int mg = m0 + mw + 16 * i + quad * 4 + r;
        outp[(size_t)mg * DD + colg] = acc[i][j][r] + bias[colg];
      }
    }
}

// ---------------- MFMA flash attention: split-pair blocks, 8 waves --------
// (R9-proven.) Grid 512: each (qp,h,b) pair splits into two `half` blocks;
// waves 0-3 light tile (QT=qp), waves 4-7 heavy mirror (QT=15-qp); each
// wave owns ONE 16-row strip. 2 blocks/CU x 8 waves = 4 waves/SIMD.
// XCD swizzle: all 16 blocks of a (b,h) share lid mod 32 -> same XCD.
// PV B-operand = LANE-LOCAL P (V stored k-permuted by gemm_qkv).
__global__ __launch_bounds__(512) void attn_mfma_kernel(
    const u16* __restrict__ Qw, const u16* __restrict__ Kw,
    const u16* __restrict__ Vt, u16* __restrict__ Ow,
    const int* __restrict__ eff) {
  __shared__ u16 KL[2][8 * 64 * 8];   // [buf][frag fk=mt*2+j][lane][8] : 8 KB/buf
  __shared__ u16 VL[2][8 * 64 * 8];   // [buf][frag fv=dt*2+j][lane][8]
  const int w = threadIdx.x >> 6, lane = threadIdx.x & 63;
  const int l15 = lane & 15, q4 = lane >> 4;
  const int lid = blockIdx.x;
  const int qp = lid >> 6;                               // 0..7
  const int half = (lid >> 5) & 1;                       // 64-row half of tile
  const int c  = lid & 31;
  const int h = c & 15, b = c >> 4;
  const int wg = w >> 2, wl = w & 3;
  const int QT = wg ? (SB / 128 - 1 - qp) : qp;          // light / heavy pair
  const int limit = SB - eff[b];                         // valid cols [0, limit)
  const size_t bh = ((size_t)b * NH + h) * (SB * HDIM);

  const int rowbase = QT * 128 + half * 64 + wl * 16;    // 16-row strip per wave

  bf16x8 qf[2];
  {
    const u16* qp0 = Qw + bh + (size_t)(rowbase + l15) * HDIM + q4 * 8;
    qf[0] = *(const bf16x8*)qp0;
    qf[1] = *(const bf16x8*)(qp0 + 32);
  }

  f4 acc[4];
#pragma unroll
  for (int dt = 0; dt < 4; dt++) acc[dt] = (f4)0.f;
  float l_run = 0.f;   // per-lane partial row sum (16 cols/lane)

  // block-uniform tile count = heavy tile's k-range (same for both halves)
  const int kendB = min((SB / 128 - 1 - qp) * 128 + 127, limit - 1);
  const int ntiles = (kendB >> 6) + 1;
  const int wkend = min(rowbase + 15, limit - 1);

  // stage(tile, buf): wave w stages frags {2w, 2w+1} of 16 (0-7 K, 8-15 V).
#define STAGE_TILE(TILE, BUF)                                                   \
  {                                                                             \
    const int colb_ = (TILE) * 64;                                              \
    _Pragma("unroll") for (int f = 0; f < 2; f++) {                             \
      int fr = w * 2 + f;                                                       \
      if (fr < 8) {                                                             \
        int mt = fr >> 1, j = fr & 1;                                           \
        gl_lds16(Kw + bh + (size_t)(colb_ + mt * 16 + l15) * HDIM + q4 * 8 + j * 32, \
                 &KL[BUF][fr * 512]);                                           \
      } else {                                                                  \
        int fv = fr - 8, dt = fv >> 1, j = fv & 1;                              \
        gl_lds16(Vt + bh + (size_t)(dt * 16 + l15) * SB + colb_ + q4 * 8 + j * 32, \
                 &VL[BUF][fv * 512]);                                           \
      }                                                                         \
    }                                                                           \
  }

  STAGE_TILE(0, 0)
  __syncthreads();

  for (int kt = 0; kt < ntiles; kt++) {
    const int cur = kt & 1;
    const int colb = kt * 64;
    if (kt + 1 < ntiles) STAGE_TILE(kt + 1, cur ^ 1)

    if (colb <= wkend) {   // wave-uniform: tile has at least one valid col
      // ---- S^T = K · Q^T (K frags from LDS) ----
      f4 sa[4];
      __builtin_amdgcn_s_setprio(1);
#pragma unroll
      for (int mt = 0; mt < 4; mt++) {
        bf16x8 k0 = *(const bf16x8*)&KL[cur][(mt * 2 + 0) * 512 + lane * 8];
        bf16x8 k1 = *(const bf16x8*)&KL[cur][(mt * 2 + 1) * 512 + lane * 8];
        f4 s0 = (f4)0.f;
        s0 = __builtin_amdgcn_mfma_f32_16x16x32_bf16(k0, qf[0], s0, 0, 0, 0);
        s0 = __builtin_amdgcn_mfma_f32_16x16x32_bf16(k1, qf[1], s0, 0, 0, 0);
        sa[mt] = s0;
      }
      __builtin_amdgcn_s_setprio(0);

      // ---- mask + fixed-reference softmax weights ----
      u32 pk[4][2];
      {
        const int rg = rowbase + l15;
        const bool needmask = (colb + 63 > rowbase) || (colb + 63 >= limit);
        if (needmask) {
#pragma unroll
          for (int mt = 0; mt < 4; mt++)
#pragma unroll
            for (int r = 0; r < 4; r++) {
              int col = colb + mt * 16 + q4 * 4 + r;
              if (col > rg || col >= limit) sa[mt][r] = -3.0e38f;
            }
        }
        float lsum = 0.f;
#pragma unroll
        for (int mt = 0; mt < 4; mt++) {
          float p0 = exp2f(sa[mt][0]);   // masked -> exp2(-3e38) = 0 exactly
          float p1 = exp2f(sa[mt][1]);
          float p2 = exp2f(sa[mt][2]);
          float p3 = exp2f(sa[mt][3]);
          lsum += (p0 + p1) + (p2 + p3);
          pk[mt][0] = (__float_as_uint(p1) & 0xFFFF0000u) | (__float_as_uint(p0) >> 16);
          pk[mt][1] = (__float_as_uint(p3) & 0xFFFF0000u) | (__float_as_uint(p2) >> 16);
        }
        l_run += lsum;
      }

      // ---- PV: B-operand = LANE-LOCAL packed P (k-perm matches Vt) ----
      union { u32 wds[4]; bf16x8 v; } ub0, ub1;
      ub0.wds[0] = pk[0][0]; ub0.wds[1] = pk[0][1];
      ub0.wds[2] = pk[1][0]; ub0.wds[3] = pk[1][1];
      ub1.wds[0] = pk[2][0]; ub1.wds[1] = pk[2][1];
      ub1.wds[2] = pk[3][0]; ub1.wds[3] = pk[3][1];
      __builtin_amdgcn_s_setprio(1);
#pragma unroll
      for (int dt = 0; dt < 4; dt++) {
        bf16x8 v0 = *(const bf16x8*)&VL[cur][(dt * 2 + 0) * 512 + lane * 8];
        bf16x8 v1 = *(const bf16x8*)&VL[cur][(dt * 2 + 1) * 512 + lane * 8];
        acc[dt] = __builtin_amdgcn_mfma_f32_16x16x32_bf16(v0, ub0.v, acc[dt], 0, 0, 0);
        acc[dt] = __builtin_amdgcn_mfma_f32_16x16x32_bf16(v1, ub1.v, acc[dt], 0, 0, 0);
      }
      __builtin_amdgcn_s_setprio(0);
    }
    __syncthreads();   // reads of buf cur done; prefetch into cur^1 drained
  }

  // ---- epilogue: reduce l across lanes, normalize, store (B,S,H,HD) ----
  {
    float lt = l_run;
    lt += __shfl_xor(lt, 16);
    lt += __shfl_xor(lt, 32);
    const float linv = 1.0f / lt;
    const int rg = rowbase + l15;
    const size_t obase = (((size_t)b * SB + rg) * NH + h) * HDIM + q4 * 4;
#pragma unroll
    for (int dt = 0; dt < 4; dt++) {
      u16x4 o;
      o[0] = f2bf(acc[dt][0] * linv);
      o[1] = f2bf(acc[dt][1] * linv);
      o[2] = f2bf(acc[dt][2] * linv);
      o[3] = f2bf(acc[dt][3] * linv);
      *(u16x4*)(Ow + obase + dt * 16) = o;
    }
  }
}

extern "C" void kernel_launch(void* const* d_in, const int* in_sizes, int n_in,
                              void* d_out, int out_size, void* d_ws, size_t ws_size,
                              hipStream_t stream) {
  (void)in_sizes; (void)n_in; (void)out_size;
  const float* x  = (const float*)d_in[0];
  const int*   eff = (const int*)d_in[1];
  const float* Wq = (const float*)d_in[2];
  const float* bq = (const float*)d_in[3];
  const float* Wk = (const float*)d_in[4];
  const float* bk = (const float*)d_in[5];
  const float* Wv = (const float*)d_in[6];
  const float* bv = (const float*)d_in[7];
  const float* Wo = (const float*)d_in[8];
  const float* bo = (const float*)d_in[9];
  float* out = (float*)d_out;

  char* ws = (char*)d_ws;
  u16* Qw = (u16*)(ws);                        // 8 MB  bf16 (B,H,S,HD), pre-scaled
  u16* Kw = (u16*)(ws + (8u << 20));           // 8 MB  bf16 (B,H,S,HD)
  u16* Vt = (u16*)(ws + (16u << 20));          // 8 MB  bf16 (B,H,HD,S)  transposed+k-perm
  u16* Ow = (u16*)(ws + (24u << 20));          // 8 MB  bf16 (B,S,H,HD)
  u16* xb = (u16*)(ws + (24u << 20));          // aliases Ow: xb dead before attn writes Ow
  u16* Wb3 = (u16*)(ws + (32u << 20));         // 6 MB  stacked bf16 [Wq;Wk;Wv]
  float* cosT = (float*)(ws + (38u << 20));    // 256 KB
  float* sinT = (float*)(ws + (38u << 20) + (256u << 10));

  // Wo bf16: separate region if workspace allows (fused cvt in prep, one
  // fewer dispatch); else fall back to reusing Wb3 after gemm_qkv.
  size_t wob_off = (38u << 20) + (512u << 10);
  int nwo = (ws_size >= wob_off + (2u << 20)) ? 512 : 0;
  u16* WoB = nwo ? (u16*)(ws + wob_off) : Wb3;

  hipLaunchKernelGGL(prep_kernel, dim3(3840 + nwo), dim3(256), 0, stream,
                     x, Wq, Wk, Wv, Wo, xb, Wb3, WoB, cosT, sinT, nwo);

  hipLaunchKernelGGL(gemm_qkv_fused_kernel, dim3(768), dim3(512), 0, stream,
                     xb, Wb3, bq, bk, bv, Qw, Kw, Vt, cosT, sinT);

  if (!nwo)
    hipLaunchKernelGGL(cvt_bf16_kernel, dim3(512), dim3(256), 0, stream, Wo, WoB);

  hipLaunchKernelGGL(attn_mfma_kernel, dim3(512), dim3(512), 0, stream,
                     Qw, Kw, Vt, Ow, eff);

  hipLaunchKernelGGL(gemm_out_kernel, dim3(512), dim3(256), 0, stream, Ow, WoB, bo, out);
}

// Round 15
// 175.303 us; speedup vs baseline: 1.1346x; 1.0511x over previous
//
#include <hip/hip_runtime.h>

#define SB   2048   // sequence length S
#define DD   1024   // model dim D
#define NH   16     // heads
#define HDIM 64     // head dim
#define NB   2      // batch

typedef float f4 __attribute__((ext_vector_type(4)));
typedef __bf16 bf16x8 __attribute__((ext_vector_type(8)));
typedef unsigned short u16;
typedef unsigned int u32;
typedef unsigned long long u64;
typedef u16 u16x8 __attribute__((ext_vector_type(8)));
typedef u16 u16x4 __attribute__((ext_vector_type(4)));

// Q is pre-scaled by 1/sqrt(HD) * log2(e) so attention works in exp2 domain.
#define QSCALE 0.1803368801111f

__device__ __forceinline__ u16 f2bf(float f) {
  unsigned u = __float_as_uint(f);
  u += 0x7FFFu + ((u >> 16) & 1u);   // RNE to bf16
  return (u16)(u >> 16);
}

// async global->LDS, 16 B per lane; LDS dest = base + lane*16 (wave-uniform base)
typedef __attribute__((address_space(3))) unsigned int lds_uint;
typedef __attribute__((address_space(1))) const unsigned int glb_uint;
__device__ __forceinline__ void gl_lds16(const void* g, void* l) {
  __builtin_amdgcn_global_load_lds((glb_uint*)g, (lds_uint*)l, 16, 0, 0);
}

__device__ __forceinline__ void cvt8(const float* __restrict__ src,
                                     u16* __restrict__ dst, size_t i) {
  f4 a = *(const f4*)(src + 8 * i);
  f4 b = *(const f4*)(src + 8 * i + 4);
  u16x8 o;
  o[0] = f2bf(a[0]); o[1] = f2bf(a[1]); o[2] = f2bf(a[2]); o[3] = f2bf(a[3]);
  o[4] = f2bf(b[0]); o[5] = f2bf(b[1]); o[6] = f2bf(b[2]); o[7] = f2bf(b[3]);
  *(u16x8*)(dst + 8 * i) = o;
}

// ---------------- prep: x cvt + Wq/Wk/Wv (+Wo) cvt + RoPE tables ----------
// x blocks XCD-PERMUTED (R12-proven): block on XCD g converts xb rows
// [512g, 512g+512) = gemm_qkv XCD g's m-panel -> xb lands dirty in the
// CONSUMER's L2. Weights use NORMAL stores (R13 falsified NT stores).
__global__ __launch_bounds__(256) void prep_kernel(
    const float* __restrict__ x, const float* __restrict__ Wq,
    const float* __restrict__ Wk, const float* __restrict__ Wv,
    const float* __restrict__ Wo,
    u16* __restrict__ xb, u16* __restrict__ Wb3, u16* __restrict__ WoB,
    float* __restrict__ cosT, float* __restrict__ sinT, int nwo) {
  int bid = blockIdx.x, t = threadIdx.x;
  if (bid < 2048) {
    int b2 = ((bid & 7) << 8) | (bid >> 3);   // bijective XCD-match permutation
    cvt8(x, xb, (size_t)b2 * 256 + t);
  } else if (bid < 2560) {
    cvt8(Wq, Wb3, (size_t)(bid - 2048) * 256 + t);
  } else if (bid < 3072) {
    cvt8(Wk, Wb3 + (1u << 20), (size_t)(bid - 2560) * 256 + t);
  } else if (bid < 3584) {
    cvt8(Wv, Wb3 + (2u << 20), (size_t)(bid - 3072) * 256 + t);
  } else if (bid < 3584 + nwo) {
    cvt8(Wo, WoB, (size_t)(bid - 3584) * 256 + t);
  } else {
    int idx = (bid - 3584 - nwo) * 256 + t;   // 0..65535 = S*32
    int tt = idx & 31, s = idx >> 5;
    float inv = powf(10000.0f, -2.0f * (float)tt / 64.0f);
    float ang = (float)s * inv;
    cosT[idx] = cosf(ang);
    sinT[idx] = sinf(ang);
  }
}

// ---------------- fp32 -> bf16 bulk convert (Wo fallback path) ------------
__global__ __launch_bounds__(256) void cvt_bf16_kernel(const float* __restrict__ src,
                                                       u16* __restrict__ dst) {
  cvt8(src, dst, (size_t)blockIdx.x * 256 + threadIdx.x);
}

// ---------------- Fused QKV GEMM: 128x128 tile, BK=128, 512 threads -------
// BK=64 -> 128: HALVES the barrier count (32 -> 16) and doubles MFMA per
// barrier (16 -> 32/wave) — attacks the vmcnt-drain amortization that
// keeps this kernel latency-bound (R14: all pipes <30%). LDS 64 KB
// (A 32K + B 32K, single buffer) -> 2 blocks/CU (risk: m132-style
// occupancy loss; revert if dur >= 50 us). Rows are 256 B = 16 granules:
// swizzle phys = lg ^ (row & 15); read granule (kh*4+quad) ^ (R & 15),
// kh in 0..3 — 16 lanes spread over 32 banks, 2-way = free.
// 1-D grid 768, XCD-decoded: m0 panel owned by XCD lid&7 (R12-proven).
// Epilogue (V): k-permuted merged u16x8 (unchanged).
// Epilogue (Q/K): SINGLE-PASS now — 64 KB smem gives every wave a private
// 8 KB transpose slice (wave*8192); no pass loop, no epilogue barriers.
__global__ __launch_bounds__(512, 4) void gemm_qkv_fused_kernel(
    const u16* __restrict__ A, const u16* __restrict__ W3,
    const float* __restrict__ bq, const float* __restrict__ bk,
    const float* __restrict__ bv,
    u16* __restrict__ Qw, u16* __restrict__ Kw, u16* __restrict__ Vt,
    const float* __restrict__ cosT, const float* __restrict__ sinT) {
  const int K = DD;
  __shared__ char smem[65536];
  u16* As = (u16*)smem;              // 32 KB: 128 rows x 128
  u16* Bs = (u16*)(smem + 32768);    // 32 KB
  const int t = threadIdx.x;
  const int wave = t >> 6, lane = t & 63;
  const int lid = blockIdx.x;                      // 0..767
  const int m0 = ((lid & 7) * 4 + ((lid >> 3) & 3)) * 128;
  const int n0 = (lid >> 5) * 128;
  const int mw = (wave >> 1) * 32, nw = (wave & 1) * 64;
  const int quad = lane >> 4, l15 = lane & 15;
  const int srow = lane >> 4, sgran = lane & 15;  // staging: 4 rows x 16 granules
  const u16* Ab = A + (size_t)m0 * K;
  const u16* Bb = W3 + (size_t)n0 * K;
  f4 acc[2][4];
#pragma unroll
  for (int i = 0; i < 2; i++)
#pragma unroll
    for (int j = 0; j < 4; j++) acc[i][j] = (f4)0.f;

  for (int kt = 0; kt < K; kt += 128) {
#pragma unroll
    for (int is = 0; is < 4; is++) {
      int r = wave * 16 + is * 4 + srow;
      int lg = sgran ^ (r & 15);
      gl_lds16(Ab + (size_t)r * K + kt + lg * 8, &As[(wave * 16 + is * 4) * 128]);
      gl_lds16(Bb + (size_t)r * K + kt + lg * 8, &Bs[(wave * 16 + is * 4) * 128]);
    }
    __syncthreads();
#pragma unroll
    for (int kh = 0; kh < 4; kh++) {
      bf16x8 af[2], bfr[4];
#pragma unroll
      for (int i = 0; i < 2; i++) {
        int R = mw + 16 * i + l15;
        af[i] = *(const bf16x8*)&As[R * 128 + ((kh * 4 + quad) ^ (R & 15)) * 8];
      }
#pragma unroll
      for (int j = 0; j < 4; j++) {
        int Rb = nw + 16 * j + l15;
        bfr[j] = *(const bf16x8*)&Bs[Rb * 128 + ((kh * 4 + quad) ^ (Rb & 15)) * 8];
      }
#pragma unroll
      for (int i = 0; i < 2; i++)
#pragma unroll
        for (int j = 0; j < 4; j++)
          acc[i][j] = __builtin_amdgcn_mfma_f32_16x16x32_bf16(af[i], bfr[j],
                                                              acc[i][j], 0, 0, 0);
    }
    __syncthreads();
  }

  // ---- epilogue: block n-range (128) never crosses a 1024 boundary -> the
  // output routing (Q/K/V) is block-uniform.
  const int which = n0 >> 10;                    // 0=Q 1=K 2=V
  const int hh = ((n0 & 1023) + nw) >> 6;        // head index (wave-uniform)
  const int cb = (n0 + nw) & 1023;               // col base, multiple of 64

  if (which == 2) {
    // V: transposed store (B,H,HD,S), k-permuted within 32-blocks.
#pragma unroll
    for (int j = 0; j < 4; j++) {
      const int dh = 16 * j + l15;
      const float bval = bv[cb + 16 * j + l15];
      int mg0 = m0 + mw;
      int b = mg0 >> 11, sr0 = mg0 & (SB - 1);
      u16x8 o;
#pragma unroll
      for (int r = 0; r < 4; r++) o[r] = f2bf(acc[0][j][r] + bval);
#pragma unroll
      for (int r = 0; r < 4; r++) o[4 + r] = f2bf(acc[1][j][r] + bval);
      *(u16x8*)(Vt + ((size_t)(b * NH + hh) * HDIM + dh) * SB +
                (sr0 | (quad << 3))) = o;
    }
  } else {
    // Q/K: LDS transpose -> in-register RoPE -> coalesced u16x8 stores.
    // Single pass: every wave has a private 8 KB slice (8 x 8 KB = 64 KB).
    u16* dst = which ? Kw : Qw;
    const float* barr = which ? bk : bq;
    const float scale = which ? 1.0f : QSCALE;
    float bvj[4];
#pragma unroll
    for (int j = 0; j < 4; j++) bvj[j] = barr[cb + 16 * j + l15];
    const int kk = lane >> 1, hf = lane & 1;
    float* sl = (float*)(smem + wave * 8192);    // 32 rows x 64 f32
    // write phase: lane(quad,l15) scatters acc into [row][rot(col)]
#pragma unroll
    for (int il = 0; il < 2; il++) {
#pragma unroll
      for (int j = 0; j < 4; j++) {
        const int q = 4 * j + (l15 >> 2);
        const int w = l15 & 3;
#pragma unroll
        for (int r = 0; r < 4; r++) {
          const int row = il * 16 + quad * 4 + r;
          sl[(row << 6) + (((q + row) & 15) << 2) + w] =
              (acc[il][j][r] + bvj[j]) * scale;
        }
      }
    }
    asm volatile("s_waitcnt lgkmcnt(0)" ::: "memory");
    // read phase (STREAMING): lane -> (row kk, col-half hf*32).
    const int m = m0 + mw + kk;
    const int b = m >> 11, sr = m & (SB - 1);
    const float* ct = cosT + sr * 32 + hf * 16;
    const float* st2 = sinT + sr * 32 + hf * 16;
    u16* op = dst + (((size_t)(b * NH + hh)) * SB + sr) * HDIM + hf * 32;
#pragma unroll
    for (int q8 = 0; q8 < 4; q8++) {
      f4 c4 = *(const f4*)(ct + q8 * 4);
      f4 s4 = *(const f4*)(st2 + q8 * 4);
      const int qc0 = hf * 8 + q8 * 2;           // two consecutive col-quads
      f4 v0 = *(const f4*)(sl + (kk << 6) + (((qc0 + kk) & 15) << 2));
      f4 v1 = *(const f4*)(sl + (kk << 6) + (((qc0 + 1 + kk) & 15) << 2));
      u16x8 o;
      o[0] = f2bf(v0[0] * c4[0] - v0[1] * s4[0]);
      o[1] = f2bf(v0[0] * s4[0] + v0[1] * c4[0]);
      o[2] = f2bf(v0[2] * c4[1] - v0[3] * s4[1]);
      o[3] = f2bf(v0[2] * s4[1] + v0[3] * c4[1]);
      o[4] = f2bf(v1[0] * c4[2] - v1[1] * s4[2]);
      o[5] = f2bf(v1[0] * s4[2] + v1[1] * c4[2]);
      o[6] = f2bf(v1[2] * c4[3] - v1[3] * s4[3]);
      o[7] = f2bf(v1[2] * s4[3] + v1[3] * c4[3]);
      *(u16x8*)(op + q8 * 8) = o;
    }
  }
}

// ---------------- Output projection GEMM: 128x64 tile, BK=64, 256 thr -----
// R10/R11-PROVEN version. 1-D grid 512, XCD-decoded: g = lid&7,
// mb = g*4 + (lid>>3&3), nb = lid>>5.
__global__ __launch_bounds__(256) void gemm_out_kernel(
    const u16* __restrict__ A, const u16* __restrict__ W,
    const float* __restrict__ bias, float* __restrict__ outp) {
  const int K = DD;
  __shared__ u16 As[128 * 64];   // 16 KB
  __shared__ u16 Bs[64 * 64];    // 8 KB
  const int t = threadIdx.x;
  const int wave = t >> 6, lane = t & 63;
  const int lid = blockIdx.x;                      // 0..511
  const int m0 = ((lid & 7) * 4 + ((lid >> 3) & 3)) * 128;
  const int n0 = (lid >> 5) * 64;
  const int mw = (wave >> 1) * 64, nw = (wave & 1) * 32;
  const int quad = lane >> 4, l15 = lane & 15;
  const int srow = lane >> 3, sgran = lane & 7;
  const u16* Ab = A + (size_t)m0 * K;
  const u16* Bb = W + (size_t)n0 * K;
  f4 acc[4][2];
#pragma unroll
  for (int i = 0; i < 4; i++)
#pragma unroll
    for (int j = 0; j < 2; j++) acc[i][j] = (f4)0.f;

  for (int kt = 0; kt < K; kt += 64) {
#pragma unroll
    for (int is = 0; is < 4; is++) {
      int r = wave * 32 + is * 8 + srow;
      int lg = sgran ^ (r & 7);
      gl_lds16(Ab + (size_t)r * K + kt + lg * 8, &As[(wave * 32 + is * 8) * 64]);
    }
#pragma unroll
    for (int is = 0; is < 2; is++) {
      int r = wave * 16 + is * 8 + srow;
      int lg = sgran ^ (r & 7);
      gl_lds16(Bb + (size_t)r * K + kt + lg * 8, &Bs[(wave * 16 + is * 8) * 64]);
    }
    __syncthreads();
#pragma unroll
    for (int kh = 0; kh < 2; kh++) {
      bf16x8 af[4], bfr[2];
#pragma unroll
      for (int i = 0; i < 4; i++) {
        int R = mw + 16 * i + l15;
        af[i] = *(const bf16x8*)&As[R * 64 + ((kh * 4 + quad) ^ (R & 7)) * 8];
      }
#pragma unroll
      for (int j = 0; j < 2; j++) {
        int R = nw + 16 * j + l15;
        bfr[j] = *(const bf16x8*)&Bs[R * 64 + ((kh * 4 + quad) ^ (R & 7)) * 8];
      }
#pragma unroll
      for (int i = 0; i < 4; i++)
#pragma unroll
        for (int j = 0; j < 2; j++)
          acc[i][j] = __builtin_amdgcn_mfma_f32_16x16x32_bf16(af[i], bfr[j],
                                                              acc[i][j], 0, 0, 0);
    }
    __syncthreads();
  }
#pragma unroll
  for (int i = 0; i < 4; i++)
#pragma unroll
    for (int j = 0; j < 2; j++) {
      int colg = n0 + nw + 16 * j + l15;
#pragma unroll
      for (int r = 0; r < 4; r++) {
        int mg = m0 + mw + 16 * i + quad * 4 + r;
        outp[(size_t)mg * DD + colg] = acc[i][j][r] + bias[colg];
      }
    }
}

// ---------------- MFMA flash attention: split-pair blocks, 8 waves --------
// (R9-proven.) Grid 512: each (qp,h,b) pair splits into two `half` blocks;
// waves 0-3 light tile (QT=qp), waves 4-7 heavy mirror (QT=15-qp); each
// wave owns ONE 16-row strip. 2 blocks/CU x 8 waves = 4 waves/SIMD.
// XCD swizzle: all 16 blocks of a (b,h) share lid mod 32 -> same XCD.
// PV B-operand = LANE-LOCAL P (V stored k-permuted by gemm_qkv).
__global__ __launch_bounds__(512) void attn_mfma_kernel(
    const u16* __restrict__ Qw, const u16* __restrict__ Kw,
    const u16* __restrict__ Vt, u16* __restrict__ Ow,
    const int* __restrict__ eff) {
  __shared__ u16 KL[2][8 * 64 * 8];   // [buf][frag fk=mt*2+j][lane][8] : 8 KB/buf
  __shared__ u16 VL[2][8 * 64 * 8];   // [buf][frag fv=dt*2+j][lane][8]
  const int w = threadIdx.x >> 6, lane = threadIdx.x & 63;
  const int l15 = lane & 15, q4 = lane >> 4;
  const int lid = blockIdx.x;
  const int qp = lid >> 6;                               // 0..7
  const int half = (lid >> 5) & 1;                       // 64-row half of tile
  const int c  = lid & 31;
  const int h = c & 15, b = c >> 4;
  const int wg = w >> 2, wl = w & 3;
  const int QT = wg ? (SB / 128 - 1 - qp) : qp;          // light / heavy pair
  const int limit = SB - eff[b];                         // valid cols [0, limit)
  const size_t bh = ((size_t)b * NH + h) * (SB * HDIM);

  const int rowbase = QT * 128 + half * 64 + wl * 16;    // 16-row strip per wave

  bf16x8 qf[2];
  {
    const u16* qp0 = Qw + bh + (size_t)(rowbase + l15) * HDIM + q4 * 8;
    qf[0] = *(const bf16x8*)qp0;
    qf[1] = *(const bf16x8*)(qp0 + 32);
  }

  f4 acc[4];
#pragma unroll
  for (int dt = 0; dt < 4; dt++) acc[dt] = (f4)0.f;
  float l_run = 0.f;   // per-lane partial row sum (16 cols/lane)

  // block-uniform tile count = heavy tile's k-range (same for both halves)
  const int kendB = min((SB / 128 - 1 - qp) * 128 + 127, limit - 1);
  const int ntiles = (kendB >> 6) + 1;
  const int wkend = min(rowbase + 15, limit - 1);

  // stage(tile, buf): wave w stages frags {2w, 2w+1} of 16 (0-7 K, 8-15 V).
#define STAGE_TILE(TILE, BUF)                                                   \
  {                                                                             \
    const int colb_ = (TILE) * 64;                                              \
    _Pragma("unroll") for (int f = 0; f < 2; f++) {                             \
      int fr = w * 2 + f;                                                       \
      if (fr < 8) {                                                             \
        int mt = fr >> 1, j = fr & 1;                                           \
        gl_lds16(Kw + bh + (size_t)(colb_ + mt * 16 + l15) * HDIM + q4 * 8 + j * 32, \
                 &KL[BUF][fr * 512]);                                           \
      } else {                                                                  \
        int fv = fr - 8, dt = fv >> 1, j = fv & 1;                              \
        gl_lds16(Vt + bh + (size_t)(dt * 16 + l15) * SB + colb_ + q4 * 8 + j * 32, \
                 &VL[BUF][fv * 512]);                                           \
      }                                                                         \
    }                                                                           \
  }

  STAGE_TILE(0, 0)
  __syncthreads();

  for (int kt = 0; kt < ntiles; kt++) {
    const int cur = kt & 1;
    const int colb = kt * 64;
    if (kt + 1 < ntiles) STAGE_TILE(kt + 1, cur ^ 1)

    if (colb <= wkend) {   // wave-uniform: tile has at least one valid col
      // ---- S^T = K · Q^T (K frags from LDS) ----
      f4 sa[4];
      __builtin_amdgcn_s_setprio(1);
#pragma unroll
      for (int mt = 0; mt < 4; mt++) {
        bf16x8 k0 = *(const bf16x8*)&KL[cur][(mt * 2 + 0) * 512 + lane * 8];
        bf16x8 k1 = *(const bf16x8*)&KL[cur][(mt * 2 + 1) * 512 + lane * 8];
        f4 s0 = (f4)0.f;
        s0 = __builtin_amdgcn_mfma_f32_16x16x32_bf16(k0, qf[0], s0, 0, 0, 0);
        s0 = __builtin_amdgcn_mfma_f32_16x16x32_bf16(k1, qf[1], s0, 0, 0, 0);
        sa[mt] = s0;
      }
      __builtin_amdgcn_s_setprio(0);

      // ---- mask + fixed-reference softmax weights ----
      u32 pk[4][2];
      {
        const int rg = rowbase + l15;
        const bool needmask = (colb + 63 > rowbase) || (colb + 63 >= limit);
        if (needmask) {
#pragma unroll
          for (int mt = 0; mt < 4; mt++)
#pragma unroll
            for (int r = 0; r < 4; r++) {
              int col = colb + mt * 16 + q4 * 4 + r;
              if (col > rg || col >= limit) sa[mt][r] = -3.0e38f;
            }
        }
        float lsum = 0.f;
#pragma unroll
        for (int mt = 0; mt < 4; mt++) {
          float p0 = exp2f(sa[mt][0]);   // masked -> exp2(-3e38) = 0 exactly
          float p1 = exp2f(sa[mt][1]);
          float p2 = exp2f(sa[mt][2]);
          float p3 = exp2f(sa[mt][3]);
          lsum += (p0 + p1) + (p2 + p3);
          pk[mt][0] = (__float_as_uint(p1) & 0xFFFF0000u) | (__float_as_uint(p0) >> 16);
          pk[mt][1] = (__float_as_uint(p3) & 0xFFFF0000u) | (__float_as_uint(p2) >> 16);
        }
        l_run += lsum;
      }

      // ---- PV: B-operand = LANE-LOCAL packed P (k-perm matches Vt) ----
      union { u32 wds[4]; bf16x8 v; } ub0, ub1;
      ub0.wds[0] = pk[0][0]; ub0.wds[1] = pk[0][1];
      ub0.wds[2] = pk[1][0]; ub0.wds[3] = pk[1][1];
      ub1.wds[0] = pk[2][0]; ub1.wds[1] = pk[2][1];
      ub1.wds[2] = pk[3][0]; ub1.wds[3] = pk[3][1];
      __builtin_amdgcn_s_setprio(1);
#pragma unroll
      for (int dt = 0; dt < 4; dt++) {
        bf16x8 v0 = *(const bf16x8*)&VL[cur][(dt * 2 + 0) * 512 + lane * 8];
        bf16x8 v1 = *(const bf16x8*)&VL[cur][(dt * 2 + 1) * 512 + lane * 8];
        acc[dt] = __builtin_amdgcn_mfma_f32_16x16x32_bf16(v0, ub0.v, acc[dt], 0, 0, 0);
        acc[dt] = __builtin_amdgcn_mfma_f32_16x16x32_bf16(v1, ub1.v, acc[dt], 0, 0, 0);
      }
      __builtin_amdgcn_s_setprio(0);
    }
    __syncthreads();   // reads of buf cur done; prefetch into cur^1 drained
  }

  // ---- epilogue: reduce l across lanes, normalize, store (B,S,H,HD) ----
  {
    float lt = l_run;
    lt += __shfl_xor(lt, 16);
    lt += __shfl_xor(lt, 32);
    const float linv = 1.0f / lt;
    const int rg = rowbase + l15;
    const size_t obase = (((size_t)b * SB + rg) * NH + h) * HDIM + q4 * 4;
#pragma unroll
    for (int dt = 0; dt < 4; dt++) {
      u16x4 o;
      o[0] = f2bf(acc[dt][0] * linv);
      o[1] = f2bf(acc[dt][1] * linv);
      o[2] = f2bf(acc[dt][2] * linv);
      o[3] = f2bf(acc[dt][3] * linv);
      *(u16x4*)(Ow + obase + dt * 16) = o;
    }
  }
}

extern "C" void kernel_launch(void* const* d_in, const int* in_sizes, int n_in,
                              void* d_out, int out_size, void* d_ws, size_t ws_size,
                              hipStream_t stream) {
  (void)in_sizes; (void)n_in; (void)out_size;
  const float* x  = (const float*)d_in[0];
  const int*   eff = (const int*)d_in[1];
  const float* Wq = (const float*)d_in[2];
  const float* bq = (const float*)d_in[3];
  const float* Wk = (const float*)d_in[4];
  const float* bk = (const float*)d_in[5];
  const float* Wv = (const float*)d_in[6];
  const float* bv = (const float*)d_in[7];
  const float* Wo = (const float*)d_in[8];
  const float* bo = (const float*)d_in[9];
  float* out = (float*)d_out;

  char* ws = (char*)d_ws;
  u16* Qw = (u16*)(ws);                        // 8 MB  bf16 (B,H,S,HD), pre-scaled
  u16* Kw = (u16*)(ws + (8u << 20));           // 8 MB  bf16 (B,H,S,HD)
  u16* Vt = (u16*)(ws + (16u << 20));          // 8 MB  bf16 (B,H,HD,S)  transposed+k-perm
  u16* Ow = (u16*)(ws + (24u << 20));          // 8 MB  bf16 (B,S,H,HD)
  u16* xb = (u16*)(ws + (24u << 20));          // aliases Ow: xb dead before attn writes Ow
  u16* Wb3 = (u16*)(ws + (32u << 20));         // 6 MB  stacked bf16 [Wq;Wk;Wv]
  float* cosT = (float*)(ws + (38u << 20));    // 256 KB
  float* sinT = (float*)(ws + (38u << 20) + (256u << 10));

  // Wo bf16: separate region if workspace allows (fused cvt in prep, one
  // fewer dispatch); else fall back to reusing Wb3 after gemm_qkv.
  size_t wob_off = (38u << 20) + (512u << 10);
  int nwo = (ws_size >= wob_off + (2u << 20)) ? 512 : 0;
  u16* WoB = nwo ? (u16*)(ws + wob_off) : Wb3;

  hipLaunchKernelGGL(prep_kernel, dim3(3840 + nwo), dim3(256), 0, stream,
                     x, Wq, Wk, Wv, Wo, xb, Wb3, WoB, cosT, sinT, nwo);

  hipLaunchKernelGGL(gemm_qkv_fused_kernel, dim3(768), dim3(512), 0, stream,
                     xb, Wb3, bq, bk, bv, Qw, Kw, Vt, cosT, sinT);

  if (!nwo)
    hipLaunchKernelGGL(cvt_bf16_kernel, dim3(512), dim3(256), 0, stream, Wo, WoB);

  hipLaunchKernelGGL(attn_mfma_kernel, dim3(512), dim3(512), 0, stream,
                     Qw, Kw, Vt, Ow, eff);

  hipLaunchKernelGGL(gemm_out_kernel, dim3(512), dim3(256), 0, stream, Ow, WoB, bo, out);
}